// Round 2
// baseline (110.961 us; speedup 1.0000x reference)
//
#include <hip/hip_runtime.h>

#define SMAPE_EPS 0.001f
#define NBLOCKS   2048
#define THREADS   256

// ---------------------------------------------------------------------------
// Fused single-kernel SMAPE reduction.
//  - grid-stride float4 streaming pass, f32 accumulation
//  - per-element ratio via v_rcp_f32 (tolerance allows ~1e-7 rel. error)
//  - per-block partial -> d_ws; last block (ticket counter) reduces partials
//    and writes the final scalar. Agent-scope atomics handle cross-XCD
//    L2 non-coherence. Deterministic: reduction order is fixed; the atomic
//    only picks which block finalizes.
// ---------------------------------------------------------------------------
__global__ __launch_bounds__(THREADS) void smape_fused_kernel(
    const float* __restrict__ pred,
    const float* __restrict__ targ,
    float* __restrict__ out,
    float* __restrict__ partial,          // [NBLOCKS]
    unsigned int* __restrict__ ticket,    // zeroed by hipMemsetAsync each call
    long long n4,                         // number of float4 elements
    long long n,                          // total scalar elements
    float scale)
{
    const float4* __restrict__ p4 = reinterpret_cast<const float4*>(pred);
    const float4* __restrict__ t4 = reinterpret_cast<const float4*>(targ);

    const long long idx    = (long long)blockIdx.x * THREADS + threadIdx.x;
    const long long stride = (long long)gridDim.x * THREADS;

    float acc0 = 0.0f, acc1 = 0.0f;

    // Counted main loop (exact-trip portion) for better unroll/pipelining.
    const long long iters = n4 / stride;
    #pragma unroll 2
    for (long long k = 0; k < iters; ++k) {
        const long long i = idx + k * stride;
        float4 a = p4[i];
        float4 b = t4[i];

        float dx = fabsf(a.x) + fabsf(b.x);
        float dy = fabsf(a.y) + fabsf(b.y);
        float dz = fabsf(a.z) + fabsf(b.z);
        float dw = fabsf(a.w) + fabsf(b.w);

        float nx = fabsf(b.x - a.x) * __builtin_amdgcn_rcpf(dx);
        float ny = fabsf(b.y - a.y) * __builtin_amdgcn_rcpf(dy);
        float nz = fabsf(b.z - a.z) * __builtin_amdgcn_rcpf(dz);
        float nw = fabsf(b.w - a.w) * __builtin_amdgcn_rcpf(dw);

        acc0 += (dx >= SMAPE_EPS) ? nx : 0.0f;
        acc1 += (dy >= SMAPE_EPS) ? ny : 0.0f;
        acc0 += (dz >= SMAPE_EPS) ? nz : 0.0f;
        acc1 += (dw >= SMAPE_EPS) ? nw : 0.0f;
    }

    // Remainder of the grid-stride range.
    for (long long i = idx + iters * stride; i < n4; i += stride) {
        float4 a = p4[i];
        float4 b = t4[i];
        float dx = fabsf(a.x) + fabsf(b.x);
        float dy = fabsf(a.y) + fabsf(b.y);
        float dz = fabsf(a.z) + fabsf(b.z);
        float dw = fabsf(a.w) + fabsf(b.w);
        acc0 += (dx >= SMAPE_EPS) ? fabsf(b.x - a.x) * __builtin_amdgcn_rcpf(dx) : 0.0f;
        acc1 += (dy >= SMAPE_EPS) ? fabsf(b.y - a.y) * __builtin_amdgcn_rcpf(dy) : 0.0f;
        acc0 += (dz >= SMAPE_EPS) ? fabsf(b.z - a.z) * __builtin_amdgcn_rcpf(dz) : 0.0f;
        acc1 += (dw >= SMAPE_EPS) ? fabsf(b.w - a.w) * __builtin_amdgcn_rcpf(dw) : 0.0f;
    }

    // Scalar tail (n not divisible by 4).
    if (blockIdx.x == 0 && threadIdx.x == 0) {
        for (long long i = n4 * 4; i < n; ++i) {
            float a = pred[i];
            float b = targ[i];
            float d = fabsf(a) + fabsf(b);
            acc0 += (d >= SMAPE_EPS) ? fabsf(b - a) * __builtin_amdgcn_rcpf(d) : 0.0f;
        }
    }

    float acc = acc0 + acc1;

    // Wave-64 reduction.
    #pragma unroll
    for (int off = 32; off > 0; off >>= 1)
        acc += __shfl_down(acc, off, 64);

    // Cross-wave reduction via LDS (4 waves).
    __shared__ float warp_sums[4];
    __shared__ bool  is_last;
    const int lane = threadIdx.x & 63;
    const int wid  = threadIdx.x >> 6;
    if (lane == 0) warp_sums[wid] = acc;
    __syncthreads();

    if (threadIdx.x == 0) {
        float s = warp_sums[0] + warp_sums[1] + warp_sums[2] + warp_sums[3];
        partial[blockIdx.x] = s;
        // Release: make the partial visible device-wide, then take a ticket.
        unsigned int old = __hip_atomic_fetch_add(ticket, 1u,
                                                  __ATOMIC_ACQ_REL,
                                                  __HIP_MEMORY_SCOPE_AGENT);
        is_last = (old == (unsigned int)(gridDim.x - 1));
    }
    __syncthreads();

    // Last-arriving block performs the final reduction.
    if (is_last) {
        float facc = 0.0f;
        for (int i = threadIdx.x; i < (int)gridDim.x; i += THREADS) {
            // Agent-scope load: bypass potentially-stale per-XCD caches.
            facc += __hip_atomic_load(&partial[i], __ATOMIC_RELAXED,
                                      __HIP_MEMORY_SCOPE_AGENT);
        }
        #pragma unroll
        for (int off = 32; off > 0; off >>= 1)
            facc += __shfl_down(facc, off, 64);

        __shared__ float fin[4];
        if (lane == 0) fin[wid] = facc;
        __syncthreads();
        if (threadIdx.x == 0) {
            float total = fin[0] + fin[1] + fin[2] + fin[3];
            out[0] = total * scale;
        }
    }
}

extern "C" void kernel_launch(void* const* d_in, const int* in_sizes, int n_in,
                              void* d_out, int out_size, void* d_ws, size_t ws_size,
                              hipStream_t stream) {
    const float* pred = (const float*)d_in[0];
    const float* targ = (const float*)d_in[1];
    float* out        = (float*)d_out;

    float* partial       = (float*)d_ws;                   // NBLOCKS floats
    unsigned int* ticket = (unsigned int*)((char*)d_ws + NBLOCKS * sizeof(float));

    long long n  = (long long)in_sizes[0];
    long long n4 = n / 4;

    // result = sum(ratio) * 200 / (S*B) = total * 200 / N
    float scale = (float)(200.0 / (double)n);

    // Zero the ticket counter (graph-capture-safe async memset).
    hipMemsetAsync(ticket, 0, sizeof(unsigned int), stream);

    smape_fused_kernel<<<NBLOCKS, THREADS, 0, stream>>>(
        pred, targ, out, partial, ticket, n4, n, scale);
}

// Round 3
// 89.901 us; speedup vs baseline: 1.2343x; 1.2343x over previous
//
#include <hip/hip_runtime.h>

#define SMAPE_EPS 0.001f
#define NBLOCKS   2048
#define THREADS   256

// ---------------------------------------------------------------------------
// Fused single-kernel SMAPE reduction — fence-free finish.
//  - Round-1-proven grid-stride float4 streaming loop (while-form).
//  - Per-block partial -> ONE relaxed agent-scope HW f32 atomicAdd
//    (per-line coherence-point access; no buffer_wbl2/buffer_inv L2 walks,
//    which is what doubled Round 2's runtime).
//  - Partial-add -> ticket-increment ordering via a true data dependency on
//    the returned old value (wave can't issue the ticket RMW until the f32
//    RMW completed at the coherence point). No fences anywhere.
//  - Last block reads the accumulator (relaxed agent load) and writes out.
// ---------------------------------------------------------------------------
__global__ __launch_bounds__(THREADS) void smape_fused_kernel(
    const float* __restrict__ pred,
    const float* __restrict__ targ,
    float* __restrict__ out,
    float* __restrict__ acc_ws,           // [0] f32 accumulator (memset 0)
    unsigned int* __restrict__ ticket,    // [0] ticket counter  (memset 0)
    long long n4,                         // number of float4 elements
    long long n,                          // total scalar elements
    float scale)
{
    const float4* __restrict__ p4 = reinterpret_cast<const float4*>(pred);
    const float4* __restrict__ t4 = reinterpret_cast<const float4*>(targ);

    long long idx    = (long long)blockIdx.x * THREADS + threadIdx.x;
    long long stride = (long long)gridDim.x * THREADS;

    float acc = 0.0f;

    for (long long i = idx; i < n4; i += stride) {
        float4 a = p4[i];
        float4 b = t4[i];

        float dx = fabsf(a.x) + fabsf(b.x);
        float dy = fabsf(a.y) + fabsf(b.y);
        float dz = fabsf(a.z) + fabsf(b.z);
        float dw = fabsf(a.w) + fabsf(b.w);

        acc += (dx >= SMAPE_EPS) ? fabsf(b.x - a.x) * __builtin_amdgcn_rcpf(dx) : 0.0f;
        acc += (dy >= SMAPE_EPS) ? fabsf(b.y - a.y) * __builtin_amdgcn_rcpf(dy) : 0.0f;
        acc += (dz >= SMAPE_EPS) ? fabsf(b.z - a.z) * __builtin_amdgcn_rcpf(dz) : 0.0f;
        acc += (dw >= SMAPE_EPS) ? fabsf(b.w - a.w) * __builtin_amdgcn_rcpf(dw) : 0.0f;
    }

    // Scalar tail (n not divisible by 4) — empty for this shape, kept for safety.
    if (blockIdx.x == 0 && threadIdx.x == 0) {
        for (long long i = n4 * 4; i < n; ++i) {
            float a = pred[i];
            float b = targ[i];
            float d = fabsf(a) + fabsf(b);
            acc += (d >= SMAPE_EPS) ? fabsf(b - a) * __builtin_amdgcn_rcpf(d) : 0.0f;
        }
    }

    // Wave-64 reduction.
    #pragma unroll
    for (int off = 32; off > 0; off >>= 1)
        acc += __shfl_down(acc, off, 64);

    // Cross-wave reduction via LDS (4 waves).
    __shared__ float warp_sums[4];
    __shared__ bool  is_last;
    const int lane = threadIdx.x & 63;
    const int wid  = threadIdx.x >> 6;
    if (lane == 0) warp_sums[wid] = acc;
    __syncthreads();

    if (threadIdx.x == 0) {
        float s = warp_sums[0] + warp_sums[1] + warp_sums[2] + warp_sums[3];

        // Relaxed HW f32 atomic add — returns prior value from the
        // coherence point. No cache-maintenance instructions emitted.
        float old = __hip_atomic_fetch_add(acc_ws, s, __ATOMIC_RELAXED,
                                           __HIP_MEMORY_SCOPE_AGENT);

        // Launder `old` so the compiler cannot fold the dependency away.
        // acc_ws starts at 0 and every addend is >= 0, so old >= 0 and
        // (u >> 31) == 0 at runtime — the ticket always increments by 1,
        // but only AFTER the f32 RMW has completed device-wide.
        unsigned int u = __float_as_uint(old);
        asm volatile("" : "+v"(u));
        unsigned int t = __hip_atomic_fetch_add(ticket, 1u + (u >> 31),
                                                __ATOMIC_RELAXED,
                                                __HIP_MEMORY_SCOPE_AGENT);
        is_last = (t == (unsigned int)(gridDim.x - 1));
    }
    __syncthreads();

    if (is_last && threadIdx.x == 0) {
        float total = __hip_atomic_load(acc_ws, __ATOMIC_RELAXED,
                                        __HIP_MEMORY_SCOPE_AGENT);
        out[0] = total * scale;
    }
}

extern "C" void kernel_launch(void* const* d_in, const int* in_sizes, int n_in,
                              void* d_out, int out_size, void* d_ws, size_t ws_size,
                              hipStream_t stream) {
    const float* pred = (const float*)d_in[0];
    const float* targ = (const float*)d_in[1];
    float* out        = (float*)d_out;

    float* acc_ws        = (float*)d_ws;                       // 4 bytes
    unsigned int* ticket = (unsigned int*)((char*)d_ws + 4);   // 4 bytes

    long long n  = (long long)in_sizes[0];
    long long n4 = n / 4;

    // result = sum(ratio) * 200 / (S*B) = total * 200 / N
    float scale = (float)(200.0 / (double)n);

    // Zero accumulator + ticket (graph-capture-safe async memset, 8 bytes).
    hipMemsetAsync(d_ws, 0, 8, stream);

    smape_fused_kernel<<<NBLOCKS, THREADS, 0, stream>>>(
        pred, targ, out, acc_ws, ticket, n4, n, scale);
}

// Round 4
// 47.567 us; speedup vs baseline: 2.3328x; 1.8900x over previous
//
#include <hip/hip_runtime.h>

#define SMAPE_EPS 0.001f
#define NBLOCKS   2048
#define THREADS   256

// ---------------------------------------------------------------------------
// Kernel 1: grid-stride float4 streaming pass, unrolled x2 so four
// independent 16B loads are in flight per thread per iteration.
// 32-bit indexing (n4 < 2^31) halves address-calc VALU.
// Per-block partial -> plain store to d_ws (no atomics; the R2/R3 fused
// finishes lost 40-60us to same-address fabric-atomic serialization and
// agent-scope fence L2 walks -- two-kernel structure is strictly better).
// ---------------------------------------------------------------------------
__global__ __launch_bounds__(THREADS) void smape_partial_kernel(
    const float* __restrict__ pred,
    const float* __restrict__ targ,
    float* __restrict__ partial,
    int n4,                 // number of float4 elements (fits in int)
    long long n)            // total scalar elements (for tail)
{
    const float4* __restrict__ p4 = reinterpret_cast<const float4*>(pred);
    const float4* __restrict__ t4 = reinterpret_cast<const float4*>(targ);

    const int idx    = blockIdx.x * THREADS + threadIdx.x;
    const int stride = gridDim.x * THREADS;

    float acc0 = 0.0f, acc1 = 0.0f;

    int i = idx;
    // Main unrolled-by-2 loop: cluster 4 independent loads before any use.
    for (; i + stride < n4; i += 2 * stride) {
        float4 a0 = p4[i];
        float4 b0 = t4[i];
        float4 a1 = p4[i + stride];
        float4 b1 = t4[i + stride];

        float d0x = fabsf(a0.x) + fabsf(b0.x);
        float d0y = fabsf(a0.y) + fabsf(b0.y);
        float d0z = fabsf(a0.z) + fabsf(b0.z);
        float d0w = fabsf(a0.w) + fabsf(b0.w);
        acc0 += (d0x >= SMAPE_EPS) ? fabsf(b0.x - a0.x) * __builtin_amdgcn_rcpf(d0x) : 0.0f;
        acc1 += (d0y >= SMAPE_EPS) ? fabsf(b0.y - a0.y) * __builtin_amdgcn_rcpf(d0y) : 0.0f;
        acc0 += (d0z >= SMAPE_EPS) ? fabsf(b0.z - a0.z) * __builtin_amdgcn_rcpf(d0z) : 0.0f;
        acc1 += (d0w >= SMAPE_EPS) ? fabsf(b0.w - a0.w) * __builtin_amdgcn_rcpf(d0w) : 0.0f;

        float d1x = fabsf(a1.x) + fabsf(b1.x);
        float d1y = fabsf(a1.y) + fabsf(b1.y);
        float d1z = fabsf(a1.z) + fabsf(b1.z);
        float d1w = fabsf(a1.w) + fabsf(b1.w);
        acc0 += (d1x >= SMAPE_EPS) ? fabsf(b1.x - a1.x) * __builtin_amdgcn_rcpf(d1x) : 0.0f;
        acc1 += (d1y >= SMAPE_EPS) ? fabsf(b1.y - a1.y) * __builtin_amdgcn_rcpf(d1y) : 0.0f;
        acc0 += (d1z >= SMAPE_EPS) ? fabsf(b1.z - a1.z) * __builtin_amdgcn_rcpf(d1z) : 0.0f;
        acc1 += (d1w >= SMAPE_EPS) ? fabsf(b1.w - a1.w) * __builtin_amdgcn_rcpf(d1w) : 0.0f;
    }
    // Remainder (at most one grid-stride step).
    for (; i < n4; i += stride) {
        float4 a = p4[i];
        float4 b = t4[i];
        float dx = fabsf(a.x) + fabsf(b.x);
        float dy = fabsf(a.y) + fabsf(b.y);
        float dz = fabsf(a.z) + fabsf(b.z);
        float dw = fabsf(a.w) + fabsf(b.w);
        acc0 += (dx >= SMAPE_EPS) ? fabsf(b.x - a.x) * __builtin_amdgcn_rcpf(dx) : 0.0f;
        acc1 += (dy >= SMAPE_EPS) ? fabsf(b.y - a.y) * __builtin_amdgcn_rcpf(dy) : 0.0f;
        acc0 += (dz >= SMAPE_EPS) ? fabsf(b.z - a.z) * __builtin_amdgcn_rcpf(dz) : 0.0f;
        acc1 += (dw >= SMAPE_EPS) ? fabsf(b.w - a.w) * __builtin_amdgcn_rcpf(dw) : 0.0f;
    }

    // Scalar tail (n not divisible by 4) — empty for this shape.
    if (blockIdx.x == 0 && threadIdx.x == 0) {
        for (long long j = (long long)n4 * 4; j < n; ++j) {
            float a = pred[j];
            float b = targ[j];
            float d = fabsf(a) + fabsf(b);
            acc0 += (d >= SMAPE_EPS) ? fabsf(b - a) * __builtin_amdgcn_rcpf(d) : 0.0f;
        }
    }

    float acc = acc0 + acc1;

    // Wave-64 reduction.
    #pragma unroll
    for (int off = 32; off > 0; off >>= 1)
        acc += __shfl_down(acc, off, 64);

    // Cross-wave reduction via LDS (256 threads = 4 waves).
    __shared__ float warp_sums[4];
    const int lane = threadIdx.x & 63;
    const int wid  = threadIdx.x >> 6;
    if (lane == 0) warp_sums[wid] = acc;
    __syncthreads();

    if (threadIdx.x == 0) {
        partial[blockIdx.x] = warp_sums[0] + warp_sums[1] + warp_sums[2] + warp_sums[3];
    }
}

// ---------------------------------------------------------------------------
// Kernel 2: single-block final reduction of per-block partials.
// ---------------------------------------------------------------------------
__global__ __launch_bounds__(THREADS) void smape_final_kernel(
    const float* __restrict__ partial,
    int nblocks,
    float* __restrict__ out,
    float scale)
{
    float acc = 0.0f;
    for (int i = threadIdx.x; i < nblocks; i += THREADS)
        acc += partial[i];

    #pragma unroll
    for (int off = 32; off > 0; off >>= 1)
        acc += __shfl_down(acc, off, 64);

    __shared__ float warp_sums[4];
    const int lane = threadIdx.x & 63;
    const int wid  = threadIdx.x >> 6;
    if (lane == 0) warp_sums[wid] = acc;
    __syncthreads();

    if (threadIdx.x == 0) {
        out[0] = (warp_sums[0] + warp_sums[1] + warp_sums[2] + warp_sums[3]) * scale;
    }
}

extern "C" void kernel_launch(void* const* d_in, const int* in_sizes, int n_in,
                              void* d_out, int out_size, void* d_ws, size_t ws_size,
                              hipStream_t stream) {
    const float* pred = (const float*)d_in[0];
    const float* targ = (const float*)d_in[1];
    float* out        = (float*)d_out;
    float* partial    = (float*)d_ws;   // NBLOCKS * 4 bytes

    long long n  = (long long)in_sizes[0];
    int n4       = (int)(n / 4);

    // result = sum(ratio) * 200 / (S*B) = total * 200 / N
    float scale = (float)(200.0 / (double)n);

    smape_partial_kernel<<<NBLOCKS, THREADS, 0, stream>>>(pred, targ, partial, n4, n);
    smape_final_kernel<<<1, THREADS, 0, stream>>>(partial, NBLOCKS, out, scale);
}